// Round 10
// baseline (276.167 us; speedup 1.0000x reference)
//
#include <hip/hip_runtime.h>
#include <hip/hip_bf16.h>

#define NN 50000
#define EE 800000
#define ETOT (EE + NN)
#define F 128
#define HEADS 4
#define RPB 256                   // rows per block (4 waves x 64 rows)
#define NB ((NN + 1023) / 1024)   // 49 scan chunks

typedef __bf16 bf16x8 __attribute__((ext_vector_type(8)));
typedef float  f32x4  __attribute__((ext_vector_type(4)));

// f32 -> bf16 bits, round-to-nearest-even
__device__ __forceinline__ unsigned short f32_to_bf16(float f) {
    unsigned int u = __float_as_uint(f);
    u += 0x7fffu + ((u >> 16) & 1u);
    return (unsigned short)(u >> 16);
}
__device__ __forceinline__ float bf16bits_to_f32(unsigned short s) {
    return __uint_as_float(((unsigned int)s) << 16);
}
__device__ __forceinline__ float bflo(unsigned int u) { return __uint_as_float(u << 16); }
__device__ __forceinline__ float bfhi(unsigned int u) { return __uint_as_float(u & 0xffff0000u); }

union BU { unsigned short u[8]; bf16x8 v; };

// ---------------- W pre-pack into MFMA B-fragment order, split hi/lo ----------------
// per layer: 64 KB contiguous [hi 32KB | lo 32KB]
// B-frag: lane holds B[k = kt*32 + (lane>>4)*8 + j][n = nt*16 + (lane&15)]

__global__ void wpack_k(const float* __restrict__ W1, const float* __restrict__ W2,
                        unsigned short* __restrict__ wf) {
    int t = blockIdx.x * blockDim.x + threadIdx.x;
    if (t >= 2 * 2048) return;
    int which = t >> 11;
    int rem = t & 2047;
    int lane = rem & 63;
    int tile = rem >> 6;          // kt*8+nt
    int kt = tile >> 3, nt = tile & 7;
    int q = lane >> 4, c = lane & 15;
    const float* W = which ? W2 : W1;
    BU vh, vl;
#pragma unroll
    for (int j = 0; j < 8; j++) {
        float w = W[(kt * 32 + q * 8 + j) * F + nt * 16 + c];
        unsigned short hb = f32_to_bf16(w);
        vh.u[j] = hb;
        vl.u[j] = f32_to_bf16(w - bf16bits_to_f32(hb));
    }
    size_t base_h = ((size_t)(which * 2 + 0) * 2048 + tile * 64 + lane) * 8;
    size_t base_l = ((size_t)(which * 2 + 1) * 2048 + tile * 64 + lane) * 8;
    *(bf16x8*)&wf[base_h] = vh.v;
    *(bf16x8*)&wf[base_l] = vl.v;
}

// ---------------- MFMA GEMM: 256 rows/block, 64 rows/wave (4 row-tiles) ----------------
// 196 blocks -> 1 block/CU, single round. W (hi+lo, 64KB) staged in LDS.

__launch_bounds__(256, 1)
__global__ void gemm_mfma(const float* __restrict__ A, const unsigned short* __restrict__ wf,
                          const float* __restrict__ a_src, const float* __restrict__ a_dst,
                          unsigned short* __restrict__ Cb, float* __restrict__ als,
                          float* __restrict__ ald, int M,
                          const int* __restrict__ ei, int* __restrict__ counts,
                          int* __restrict__ pos, int gemm_blocks) {
    __shared__ unsigned char smem[65536];     // W hi+lo; epilogue aliases it
    int tid = threadIdx.x;
    int w = tid >> 6, lane = tid & 63;
    int m = lane & 15, q = lane >> 4;
    int row0 = blockIdx.x * RPB + w * 64;

    // stage 64 KB of packed W into LDS (coalesced 16B per lane)
    {
        const uint4* src = (const uint4*)wf;
        uint4* dst = (uint4*)smem;
#pragma unroll
        for (int i = 0; i < 16; i++) dst[tid + i * 256] = src[tid + i * 256];
    }

    // A row pointers for the 4 row-tiles (clamped; stores guarded)
    const float* ap[4];
#pragma unroll
    for (int rt = 0; rt < 4; rt++) {
        int ar = row0 + rt * 16 + m;
        if (ar >= M) ar = 0;
        ap[rt] = A + (size_t)ar * F + q * 8;
    }
    // preload kt=0 A
    float4 a0[4], a1[4];
#pragma unroll
    for (int rt = 0; rt < 4; rt++) {
        a0[rt] = *(const float4*)(ap[rt]);
        a1[rt] = *(const float4*)(ap[rt] + 4);
    }
    __syncthreads();

    const unsigned short* lds_h = (const unsigned short*)smem;            // hi
    const unsigned short* lds_l = (const unsigned short*)(smem + 32768);  // lo

    f32x4 acc[8][4];
#pragma unroll
    for (int nt = 0; nt < 8; nt++)
#pragma unroll
        for (int rt = 0; rt < 4; rt++) acc[nt][rt] = (f32x4){0.f, 0.f, 0.f, 0.f};

#pragma unroll
    for (int kt = 0; kt < 4; kt++) {
        // prefetch next kt
        float4 n0[4], n1[4];
        if (kt < 3) {
#pragma unroll
            for (int rt = 0; rt < 4; rt++) {
                n0[rt] = *(const float4*)(ap[rt] + (kt + 1) * 32);
                n1[rt] = *(const float4*)(ap[rt] + (kt + 1) * 32 + 4);
            }
        }
        // convert current A to bf16 hi/lo fragments
        BU ah[4], al[4];
#pragma unroll
        for (int rt = 0; rt < 4; rt++) {
            float av[8] = {a0[rt].x, a0[rt].y, a0[rt].z, a0[rt].w,
                           a1[rt].x, a1[rt].y, a1[rt].z, a1[rt].w};
#pragma unroll
            for (int j = 0; j < 8; j++) {
                unsigned short hb = f32_to_bf16(av[j]);
                ah[rt].u[j] = hb;
                al[rt].u[j] = f32_to_bf16(av[j] - bf16bits_to_f32(hb));
            }
        }
#pragma unroll
        for (int nt = 0; nt < 8; nt++) {
            int bo = ((kt * 8 + nt) * 64 + lane) * 8;
            bf16x8 bh = *(const bf16x8*)&lds_h[bo];
            bf16x8 bl = *(const bf16x8*)&lds_l[bo];
#pragma unroll
            for (int rt = 0; rt < 4; rt++) {
                acc[nt][rt] = __builtin_amdgcn_mfma_f32_16x16x32_bf16(ah[rt].v, bh, acc[nt][rt], 0, 0, 0);
                acc[nt][rt] = __builtin_amdgcn_mfma_f32_16x16x32_bf16(al[rt].v, bh, acc[nt][rt], 0, 0, 0);
                acc[nt][rt] = __builtin_amdgcn_mfma_f32_16x16x32_bf16(ah[rt].v, bl, acc[nt][rt], 0, 0, 0);
            }
        }
        if (kt < 3) {
#pragma unroll
            for (int rt = 0; rt < 4; rt++) { a0[rt] = n0[rt]; a1[rt] = n1[rt]; }
        }
    }
    __syncthreads();   // all waves done reading W; reuse LDS for epilogue

    // epilogue per row-tile: C/D layout col=lane&15, row=q*4+reg -> 16x132 transpose
    float* L = (float*)smem + w * (16 * 132);
    int rr = lane >> 2;            // row within 16-row tile
    int head = lane & 3;
    int c0 = head * 32;
#pragma unroll
    for (int rt = 0; rt < 4; rt++) {
#pragma unroll
        for (int nt = 0; nt < 8; nt++)
#pragma unroll
            for (int r = 0; r < 4; r++)
                L[(q * 4 + r) * 132 + nt * 16 + m] = acc[nt][rt][r];
        // wave-synchronous LDS; compiler inserts lgkmcnt waits (in-order DS per wave)

        int gr = row0 + rt * 16 + rr;
        float v[32];
#pragma unroll
        for (int i = 0; i < 8; i++)
            *(float4*)&v[i * 4] = *(const float4*)&L[rr * 132 + c0 + i * 4];

        if (gr < M) {
#pragma unroll
            for (int i = 0; i < 4; i++) {
                uint4 pk;
                pk.x = (unsigned)f32_to_bf16(v[i * 8 + 0]) | ((unsigned)f32_to_bf16(v[i * 8 + 1]) << 16);
                pk.y = (unsigned)f32_to_bf16(v[i * 8 + 2]) | ((unsigned)f32_to_bf16(v[i * 8 + 3]) << 16);
                pk.z = (unsigned)f32_to_bf16(v[i * 8 + 4]) | ((unsigned)f32_to_bf16(v[i * 8 + 5]) << 16);
                pk.w = (unsigned)f32_to_bf16(v[i * 8 + 6]) | ((unsigned)f32_to_bf16(v[i * 8 + 7]) << 16);
                *(uint4*)&Cb[(size_t)gr * F + c0 + i * 8] = pk;
            }
            float ps = 0.f, pd = 0.f;
#pragma unroll
            for (int i = 0; i < 32; i++) {
                ps += v[i] * a_src[c0 + i];
                pd += v[i] * a_dst[c0 + i];
            }
            als[gr * HEADS + head] = ps;
            ald[gr * HEADS + head] = pd;
        }
    }

    // ---- layer-1 only: degree count + per-edge bucket offset (grid-stride tail) ----
    if (ei) {
        int stride = gemm_blocks * 256;
        for (int e = blockIdx.x * 256 + tid; e < ETOT; e += stride) {
            int dst = (e < EE) ? ei[EE + e] : (e - EE);
            pos[e] = atomicAdd(&counts[dst], 1);
        }
    }
}

// ---------------- CSR scan kernels ----------------

__launch_bounds__(1024)
__global__ void scan_block_k(const int* __restrict__ counts, int* __restrict__ row_ptr,
                             int* __restrict__ bsum, int n) {
    int tid = threadIdx.x;
    int i = blockIdx.x * 1024 + tid;
    int v = (i < n) ? counts[i] : 0;
    int lane = tid & 63;
    int wave = tid >> 6;
    int x = v;
#pragma unroll
    for (int off = 1; off < 64; off <<= 1) {
        int t = __shfl_up(x, off, 64);
        if (lane >= off) x += t;
    }
    __shared__ int wsum[16];
    if (lane == 63) wsum[wave] = x;
    __syncthreads();
    if (wave == 0) {
        int w = (lane < 16) ? wsum[lane] : 0;
#pragma unroll
        for (int off = 1; off < 16; off <<= 1) {
            int t = __shfl_up(w, off, 64);
            if (lane >= off) w += t;
        }
        if (lane < 16) wsum[lane] = w;
    }
    __syncthreads();
    int base = (wave > 0) ? wsum[wave - 1] : 0;
    int incl = base + x;
    if (i < n) row_ptr[i] = incl - v;
    if (tid == 1023) bsum[blockIdx.x] = incl;
}

__launch_bounds__(256)
__global__ void scan_add_k(int* __restrict__ row_ptr, const int* __restrict__ bsum, int n) {
    __shared__ int off_s[NB];
    if (threadIdx.x < 64) {
        int lane = threadIdx.x;
        int v = (lane < NB) ? bsum[lane] : 0;
        int x = v;
#pragma unroll
        for (int o = 1; o < 64; o <<= 1) {
            int t = __shfl_up(x, o, 64);
            if (lane >= o) x += t;
        }
        if (lane < NB) off_s[lane] = x - v;
    }
    __syncthreads();
    int i = blockIdx.x * blockDim.x + threadIdx.x;
    if (i < n) row_ptr[i] += off_s[i >> 10];
    if (i == 0) row_ptr[n] = ETOT;
}

// fill: atomic-free (uses per-edge bucket offsets recorded during counting)
__global__ void fill_k(const int* __restrict__ ei, const int* __restrict__ row_ptr,
                       const int* __restrict__ pos, int* __restrict__ csr_src) {
    int e = blockIdx.x * blockDim.x + threadIdx.x;
    if (e >= ETOT) return;
    int src, dst;
    if (e < EE) { src = ei[e]; dst = ei[EE + e]; }
    else        { src = e - EE; dst = e - EE; }
    csr_src[row_ptr[dst] + pos[e]] = src;
}

// ---------------- softmax + aggregate: wave/node, 4 groups x 16 lanes, 2-edge ILP ----

__launch_bounds__(256)
__global__ void aggregate(const unsigned short* __restrict__ hb, const float* __restrict__ als,
                          const float* __restrict__ ald, const int* __restrict__ row_ptr,
                          const int* __restrict__ csr_src, const float* __restrict__ bias,
                          float* __restrict__ out, int apply_elu) {
    int wave = threadIdx.x >> 6;
    int n = blockIdx.x * 4 + wave;
    if (n >= NN) return;
    int lane = threadIdx.x & 63;
    int g  = lane >> 4;
    int cl = lane & 15;
    int head = cl >> 2;
    float aldv = ald[n * HEADS + head];
    int jb = row_ptr[n], je = row_ptr[n + 1];

    float acc[8];
#pragma unroll
    for (int i = 0; i < 8; i++) acc[i] = 0.f;
    float den = 0.f;

    int j = jb + g;
    for (; j + 4 < je; j += 8) {
        int s0 = csr_src[j];
        int s1 = csr_src[j + 4];
        float e0 = als[s0 * HEADS + head] + aldv;
        float e1 = als[s1 * HEADS + head] + aldv;
        uint4 r0 = *(const uint4*)&hb[(size_t)s0 * F + cl * 8];
        uint4 r1 = *(const uint4*)&hb[(size_t)s1 * F + cl * 8];
        e0 = (e0 > 0.f) ? e0 : 0.2f * e0;
        e1 = (e1 > 0.f) ? e1 : 0.2f * e1;
        float p0 = __expf(e0);
        float p1 = __expf(e1);
        den += p0 + p1;
        acc[0] += p0 * bflo(r0.x); acc[1] += p0 * bfhi(r0.x);
        acc[2] += p0 * bflo(r0.y); acc[3] += p0 * bfhi(r0.y);
        acc[4] += p0 * bflo(r0.z); acc[5] += p0 * bfhi(r0.z);
        acc[6] += p0 * bflo(r0.w); acc[7] += p0 * bfhi(r0.w);
        acc[0] += p1 * bflo(r1.x); acc[1] += p1 * bfhi(r1.x);
        acc[2] += p1 * bflo(r1.y); acc[3] += p1 * bfhi(r1.y);
        acc[4] += p1 * bflo(r1.z); acc[5] += p1 * bfhi(r1.z);
        acc[6] += p1 * bflo(r1.w); acc[7] += p1 * bfhi(r1.w);
    }
    if (j < je) {
        int s = csr_src[j];
        float e = als[s * HEADS + head] + aldv;
        uint4 raw = *(const uint4*)&hb[(size_t)s * F + cl * 8];
        e = (e > 0.f) ? e : 0.2f * e;
        float p = __expf(e);
        den += p;
        acc[0] += p * bflo(raw.x); acc[1] += p * bfhi(raw.x);
        acc[2] += p * bflo(raw.y); acc[3] += p * bfhi(raw.y);
        acc[4] += p * bflo(raw.z); acc[5] += p * bfhi(raw.z);
        acc[6] += p * bflo(raw.w); acc[7] += p * bfhi(raw.w);
    }

#pragma unroll
    for (int i = 0; i < 8; i++) {
        acc[i] += __shfl_xor(acc[i], 16);
        acc[i] += __shfl_xor(acc[i], 32);
    }
    den += __shfl_xor(den, 16);
    den += __shfl_xor(den, 32);

    if (g == 0) {
        float inv = 1.f / den;
        float v[8];
#pragma unroll
        for (int i = 0; i < 8; i++) {
            v[i] = acc[i] * inv + bias[cl * 8 + i];
            if (apply_elu) v[i] = (v[i] > 0.f) ? v[i] : (__expf(v[i]) - 1.f);
        }
        float4* op = (float4*)&out[(size_t)n * F + cl * 8];
        op[0] = make_float4(v[0], v[1], v[2], v[3]);
        op[1] = make_float4(v[4], v[5], v[6], v[7]);
    }
}

// ---------------- launch ----------------

extern "C" void kernel_launch(void* const* d_in, const int* in_sizes, int n_in,
                              void* d_out, int out_size, void* d_ws, size_t ws_size,
                              hipStream_t stream) {
    const float* x   = (const float*)d_in[0];
    const int*   ei  = (const int*)d_in[1];
    const float* W1  = (const float*)d_in[2];
    const float* as1 = (const float*)d_in[3];
    const float* ad1 = (const float*)d_in[4];
    const float* b1  = (const float*)d_in[5];
    const float* W2  = (const float*)d_in[6];
    const float* as2 = (const float*)d_in[7];
    const float* ad2 = (const float*)d_in[8];
    const float* b2  = (const float*)d_in[9];
    float* out = (float*)d_out;

    char* ws = (char*)d_ws;
    size_t off = 0;
    auto alloc = [&](size_t bytes) {
        void* p = ws + off;
        off += (bytes + 255) & ~(size_t)255;
        return p;
    };
    unsigned short* hb = (unsigned short*)alloc((size_t)NN * F * 2);   // 12.8 MB
    float* als     = (float*)alloc((size_t)NN * HEADS * 4);
    float* ald     = (float*)alloc((size_t)NN * HEADS * 4);
    int*   counts  = (int*)alloc((size_t)NN * 4);
    int*   row_ptr = (int*)alloc((size_t)(NN + 1) * 4);
    int*   bsum    = (int*)alloc((size_t)NB * 4);
    int*   csr_src = (int*)alloc((size_t)ETOT * 4);       // 3.4 MB
    int*   pos     = (int*)alloc((size_t)ETOT * 4);       // 3.4 MB
    unsigned short* wf = (unsigned short*)alloc((size_t)4 * 2048 * 8 * 2);  // 128 KB

    int GG = (NN + RPB - 1) / RPB;         // 196 GEMM blocks (1 per CU, single round)
    int agg_grid = (NN + 3) / 4;

    (void)hipMemsetAsync(counts, 0, (size_t)NN * 4, stream);
    wpack_k<<<16, 256, 0, stream>>>(W1, W2, wf);

    // ---- layer 1 GEMM (MFMA, 64 rows/wave) + logits, count tail fused ----
    gemm_mfma<<<GG, 256, 0, stream>>>(x, wf, as1, ad1, hb, als, ald, NN,
                                      ei, counts, pos, GG);
    scan_block_k<<<NB, 1024, 0, stream>>>(counts, row_ptr, bsum, NN);
    scan_add_k<<<(NN + 255) / 256, 256, 0, stream>>>(row_ptr, bsum, NN);
    fill_k<<<(ETOT + 255) / 256, 256, 0, stream>>>(ei, row_ptr, pos, csr_src);
    aggregate<<<agg_grid, 256, 0, stream>>>(hb, als, ald, row_ptr, csr_src, b1, out, 1);

    // ---- layer 2 ----
    gemm_mfma<<<GG, 256, 0, stream>>>(out, wf + (size_t)2 * 2048 * 8, as2, ad2, hb, als, ald, NN,
                                      (const int*)nullptr, (int*)nullptr, (int*)nullptr, GG);
    aggregate<<<agg_grid, 256, 0, stream>>>(hb, als, ald, row_ptr, csr_src, b2, out, 0);
}

// Round 11
// 261.697 us; speedup vs baseline: 1.0553x; 1.0553x over previous
//
#include <hip/hip_runtime.h>
#include <hip/hip_bf16.h>

#define NN 50000
#define EE 800000
#define ETOT (EE + NN)
#define F 128
#define HEADS 4
#define RPB 128                   // rows per block (8 waves x 16 rows)
#define NB ((NN + 1023) / 1024)   // 49 scan chunks

typedef __bf16 bf16x8 __attribute__((ext_vector_type(8)));
typedef float  f32x4  __attribute__((ext_vector_type(4)));

// f32 -> bf16 bits, round-to-nearest-even
__device__ __forceinline__ unsigned short f32_to_bf16(float f) {
    unsigned int u = __float_as_uint(f);
    u += 0x7fffu + ((u >> 16) & 1u);
    return (unsigned short)(u >> 16);
}
__device__ __forceinline__ float bf16bits_to_f32(unsigned short s) {
    return __uint_as_float(((unsigned int)s) << 16);
}
__device__ __forceinline__ float bflo(unsigned int u) { return __uint_as_float(u << 16); }
__device__ __forceinline__ float bfhi(unsigned int u) { return __uint_as_float(u & 0xffff0000u); }

union BU { unsigned short u[8]; bf16x8 v; };

// ---------------- W pre-pack into MFMA B-fragment order, split hi/lo ----------------
// per layer: 64 KB contiguous [hi 32KB | lo 32KB]
// B-frag: lane holds B[k = kt*32 + (lane>>4)*8 + j][n = nt*16 + (lane&15)]

__global__ void wpack_k(const float* __restrict__ W1, const float* __restrict__ W2,
                        unsigned short* __restrict__ wf) {
    int t = blockIdx.x * blockDim.x + threadIdx.x;
    if (t >= 2 * 2048) return;
    int which = t >> 11;
    int rem = t & 2047;
    int lane = rem & 63;
    int tile = rem >> 6;          // kt*8+nt
    int kt = tile >> 3, nt = tile & 7;
    int q = lane >> 4, c = lane & 15;
    const float* W = which ? W2 : W1;
    BU vh, vl;
#pragma unroll
    for (int j = 0; j < 8; j++) {
        float w = W[(kt * 32 + q * 8 + j) * F + nt * 16 + c];
        unsigned short hb = f32_to_bf16(w);
        vh.u[j] = hb;
        vl.u[j] = f32_to_bf16(w - bf16bits_to_f32(hb));
    }
    size_t base_h = ((size_t)(which * 2 + 0) * 2048 + tile * 64 + lane) * 8;
    size_t base_l = ((size_t)(which * 2 + 1) * 2048 + tile * 64 + lane) * 8;
    *(bf16x8*)&wf[base_h] = vh.v;
    *(bf16x8*)&wf[base_l] = vl.v;
}

// ---------------- MFMA GEMM: 512 threads, 8 waves x 16 rows; 16 waves/CU ----------------

__launch_bounds__(512, 4)
__global__ void gemm_mfma(const float* __restrict__ A, const unsigned short* __restrict__ wf,
                          const float* __restrict__ a_src, const float* __restrict__ a_dst,
                          unsigned short* __restrict__ Cb, float* __restrict__ als,
                          float* __restrict__ ald, int M,
                          const int* __restrict__ ei, int* __restrict__ counts,
                          int* __restrict__ pos, int gemm_blocks) {
    __shared__ unsigned char smem[65536];     // W hi+lo; epilogue aliases it
    int tid = threadIdx.x;                    // 0..511
    int w = tid >> 6, lane = tid & 63;
    int m = lane & 15, q = lane >> 4;
    int row0 = blockIdx.x * RPB + w * 16;

    // stage 64 KB of packed W into LDS (coalesced 16B per lane)
    {
        const uint4* src = (const uint4*)wf;
        uint4* dst = (uint4*)smem;
#pragma unroll
        for (int i = 0; i < 8; i++) dst[tid + i * 512] = src[tid + i * 512];
    }

    // issue ALL A loads upfront (8 float4 in flight per lane)
    int ar = row0 + m; if (ar >= M) ar = 0;          // clamp; stores guarded
    const float* arow = A + (size_t)ar * F + q * 8;
    float4 a0[4], a1[4];
#pragma unroll
    for (int kt = 0; kt < 4; kt++) {
        a0[kt] = *(const float4*)(arow + kt * 32);
        a1[kt] = *(const float4*)(arow + kt * 32 + 4);
    }
    __syncthreads();

    const unsigned short* lds_h = (const unsigned short*)smem;            // hi
    const unsigned short* lds_l = (const unsigned short*)(smem + 32768);  // lo

    f32x4 acc[8];
#pragma unroll
    for (int nt = 0; nt < 8; nt++) acc[nt] = (f32x4){0.f, 0.f, 0.f, 0.f};

#pragma unroll
    for (int kt = 0; kt < 4; kt++) {
        float av[8] = {a0[kt].x, a0[kt].y, a0[kt].z, a0[kt].w,
                       a1[kt].x, a1[kt].y, a1[kt].z, a1[kt].w};
        BU ah, al;
#pragma unroll
        for (int j = 0; j < 8; j++) {
            unsigned short hb = f32_to_bf16(av[j]);
            ah.u[j] = hb;
            al.u[j] = f32_to_bf16(av[j] - bf16bits_to_f32(hb));
        }
#pragma unroll
        for (int nt = 0; nt < 8; nt++) {
            int bo = ((kt * 8 + nt) * 64 + lane) * 8;
            bf16x8 bh = *(const bf16x8*)&lds_h[bo];
            bf16x8 bl = *(const bf16x8*)&lds_l[bo];
            acc[nt] = __builtin_amdgcn_mfma_f32_16x16x32_bf16(ah.v, bh, acc[nt], 0, 0, 0);
            acc[nt] = __builtin_amdgcn_mfma_f32_16x16x32_bf16(al.v, bh, acc[nt], 0, 0, 0);
            acc[nt] = __builtin_amdgcn_mfma_f32_16x16x32_bf16(ah.v, bl, acc[nt], 0, 0, 0);
        }
    }
    __syncthreads();   // all waves done reading W; reuse LDS for epilogue

    // epilogue in 2 phases (4 waves each share 33 KB of transpose buffers)
    int rr = lane >> 2;            // row within 16-row tile
    int head = lane & 3;
    int c0 = head * 32;
    int gr = row0 + rr;
    for (int phase = 0; phase < 2; phase++) {
        if ((w >> 2) == phase) {
            float* L = (float*)smem + (w & 3) * (16 * 132);
#pragma unroll
            for (int nt = 0; nt < 8; nt++)
#pragma unroll
                for (int r = 0; r < 4; r++)
                    L[(q * 4 + r) * 132 + nt * 16 + m] = acc[nt][r];
            // wave-synchronous LDS (in-order DS per wave)
            float v[32];
#pragma unroll
            for (int i = 0; i < 8; i++)
                *(float4*)&v[i * 4] = *(const float4*)&L[rr * 132 + c0 + i * 4];
            if (gr < M) {
#pragma unroll
                for (int i = 0; i < 4; i++) {
                    uint4 pk;
                    pk.x = (unsigned)f32_to_bf16(v[i * 8 + 0]) | ((unsigned)f32_to_bf16(v[i * 8 + 1]) << 16);
                    pk.y = (unsigned)f32_to_bf16(v[i * 8 + 2]) | ((unsigned)f32_to_bf16(v[i * 8 + 3]) << 16);
                    pk.z = (unsigned)f32_to_bf16(v[i * 8 + 4]) | ((unsigned)f32_to_bf16(v[i * 8 + 5]) << 16);
                    pk.w = (unsigned)f32_to_bf16(v[i * 8 + 6]) | ((unsigned)f32_to_bf16(v[i * 8 + 7]) << 16);
                    *(uint4*)&Cb[(size_t)gr * F + c0 + i * 8] = pk;
                }
                float ps = 0.f, pd = 0.f;
#pragma unroll
                for (int i = 0; i < 32; i++) {
                    ps += v[i] * a_src[c0 + i];
                    pd += v[i] * a_dst[c0 + i];
                }
                als[gr * HEADS + head] = ps;
                ald[gr * HEADS + head] = pd;
            }
        }
        __syncthreads();
    }

    // ---- layer-1 only: degree count + per-edge bucket offset (grid-stride tail) ----
    if (ei) {
        int stride = gemm_blocks * 512;
        for (int e = blockIdx.x * 512 + tid; e < ETOT; e += stride) {
            int dst = (e < EE) ? ei[EE + e] : (e - EE);
            pos[e] = atomicAdd(&counts[dst], 1);
        }
    }
}

// ---------------- CSR scan kernels ----------------

__launch_bounds__(1024)
__global__ void scan_block_k(const int* __restrict__ counts, int* __restrict__ row_ptr,
                             int* __restrict__ bsum, int n) {
    int tid = threadIdx.x;
    int i = blockIdx.x * 1024 + tid;
    int v = (i < n) ? counts[i] : 0;
    int lane = tid & 63;
    int wave = tid >> 6;
    int x = v;
#pragma unroll
    for (int off = 1; off < 64; off <<= 1) {
        int t = __shfl_up(x, off, 64);
        if (lane >= off) x += t;
    }
    __shared__ int wsum[16];
    if (lane == 63) wsum[wave] = x;
    __syncthreads();
    if (wave == 0) {
        int w = (lane < 16) ? wsum[lane] : 0;
#pragma unroll
        for (int off = 1; off < 16; off <<= 1) {
            int t = __shfl_up(w, off, 64);
            if (lane >= off) w += t;
        }
        if (lane < 16) wsum[lane] = w;
    }
    __syncthreads();
    int base = (wave > 0) ? wsum[wave - 1] : 0;
    int incl = base + x;
    if (i < n) row_ptr[i] = incl - v;
    if (tid == 1023) bsum[blockIdx.x] = incl;
}

__launch_bounds__(256)
__global__ void scan_add_k(int* __restrict__ row_ptr, const int* __restrict__ bsum, int n) {
    __shared__ int off_s[NB];
    if (threadIdx.x < 64) {
        int lane = threadIdx.x;
        int v = (lane < NB) ? bsum[lane] : 0;
        int x = v;
#pragma unroll
        for (int o = 1; o < 64; o <<= 1) {
            int t = __shfl_up(x, o, 64);
            if (lane >= o) x += t;
        }
        if (lane < NB) off_s[lane] = x - v;
    }
    __syncthreads();
    int i = blockIdx.x * blockDim.x + threadIdx.x;
    if (i < n) row_ptr[i] += off_s[i >> 10];
    if (i == 0) row_ptr[n] = ETOT;
}

// fill: atomic-free (uses per-edge bucket offsets recorded during counting)
__global__ void fill_k(const int* __restrict__ ei, const int* __restrict__ row_ptr,
                       const int* __restrict__ pos, int* __restrict__ csr_src) {
    int e = blockIdx.x * blockDim.x + threadIdx.x;
    if (e >= ETOT) return;
    int src, dst;
    if (e < EE) { src = ei[e]; dst = ei[EE + e]; }
    else        { src = e - EE; dst = e - EE; }
    csr_src[row_ptr[dst] + pos[e]] = src;
}

// ---------------- softmax + aggregate: 16-lane group per node, 4-deep edge pipeline ----

__launch_bounds__(256)
__global__ void aggregate(const unsigned short* __restrict__ hb, const float* __restrict__ als,
                          const float* __restrict__ ald, const int* __restrict__ row_ptr,
                          const int* __restrict__ csr_src, const float* __restrict__ bias,
                          float* __restrict__ out, int apply_elu) {
    int tid = threadIdx.x;
    int lane = tid & 63;
    int g  = lane >> 4;                        // node slot within wave
    int cl = lane & 15;                        // channels cl*8 .. cl*8+7
    int n = blockIdx.x * 16 + (tid >> 6) * 4 + g;   // grid exact: 3125*16 = 50000
    int head = cl >> 2;
    float aldv = ald[n * HEADS + head];
    int jb = row_ptr[n], je = row_ptr[n + 1];

    float acc[8];
#pragma unroll
    for (int i = 0; i < 8; i++) acc[i] = 0.f;
    float den = 0.f;

    int j = jb;
    for (; j + 3 < je; j += 4) {               // 4 independent edge-chains
        int s0 = csr_src[j];
        int s1 = csr_src[j + 1];
        int s2 = csr_src[j + 2];
        int s3 = csr_src[j + 3];
        float e0 = als[s0 * HEADS + head];
        float e1 = als[s1 * HEADS + head];
        float e2 = als[s2 * HEADS + head];
        float e3 = als[s3 * HEADS + head];
        uint4 r0 = *(const uint4*)&hb[(size_t)s0 * F + cl * 8];
        uint4 r1 = *(const uint4*)&hb[(size_t)s1 * F + cl * 8];
        uint4 r2 = *(const uint4*)&hb[(size_t)s2 * F + cl * 8];
        uint4 r3 = *(const uint4*)&hb[(size_t)s3 * F + cl * 8];
        e0 += aldv; e1 += aldv; e2 += aldv; e3 += aldv;
        e0 = (e0 > 0.f) ? e0 : 0.2f * e0;
        e1 = (e1 > 0.f) ? e1 : 0.2f * e1;
        e2 = (e2 > 0.f) ? e2 : 0.2f * e2;
        e3 = (e3 > 0.f) ? e3 : 0.2f * e3;
        float p0 = __expf(e0), p1 = __expf(e1), p2 = __expf(e2), p3 = __expf(e3);
        den += (p0 + p1) + (p2 + p3);
        acc[0] += p0 * bflo(r0.x); acc[1] += p0 * bfhi(r0.x);
        acc[2] += p0 * bflo(r0.y); acc[3] += p0 * bfhi(r0.y);
        acc[4] += p0 * bflo(r0.z); acc[5] += p0 * bfhi(r0.z);
        acc[6] += p0 * bflo(r0.w); acc[7] += p0 * bfhi(r0.w);
        acc[0] += p1 * bflo(r1.x); acc[1] += p1 * bfhi(r1.x);
        acc[2] += p1 * bflo(r1.y); acc[3] += p1 * bfhi(r1.y);
        acc[4] += p1 * bflo(r1.z); acc[5] += p1 * bfhi(r1.z);
        acc[6] += p1 * bflo(r1.w); acc[7] += p1 * bfhi(r1.w);
        acc[0] += p2 * bflo(r2.x); acc[1] += p2 * bfhi(r2.x);
        acc[2] += p2 * bflo(r2.y); acc[3] += p2 * bfhi(r2.y);
        acc[4] += p2 * bflo(r2.z); acc[5] += p2 * bfhi(r2.z);
        acc[6] += p2 * bflo(r2.w); acc[7] += p2 * bfhi(r2.w);
        acc[0] += p3 * bflo(r3.x); acc[1] += p3 * bfhi(r3.x);
        acc[2] += p3 * bflo(r3.y); acc[3] += p3 * bfhi(r3.y);
        acc[4] += p3 * bflo(r3.z); acc[5] += p3 * bfhi(r3.z);
        acc[6] += p3 * bflo(r3.w); acc[7] += p3 * bfhi(r3.w);
    }
    for (; j < je; j++) {                      // tail (0..3 edges)
        int s = csr_src[j];
        float e = als[s * HEADS + head] + aldv;
        uint4 raw = *(const uint4*)&hb[(size_t)s * F + cl * 8];
        e = (e > 0.f) ? e : 0.2f * e;
        float p = __expf(e);
        den += p;
        acc[0] += p * bflo(raw.x); acc[1] += p * bfhi(raw.x);
        acc[2] += p * bflo(raw.y); acc[3] += p * bfhi(raw.y);
        acc[4] += p * bflo(raw.z); acc[5] += p * bfhi(raw.z);
        acc[6] += p * bflo(raw.w); acc[7] += p * bfhi(raw.w);
    }

    float inv = 1.f / den;
    float v[8];
#pragma unroll
    for (int i = 0; i < 8; i++) {
        v[i] = acc[i] * inv + bias[cl * 8 + i];
        if (apply_elu) v[i] = (v[i] > 0.f) ? v[i] : (__expf(v[i]) - 1.f);
    }
    float4* op = (float4*)&out[(size_t)n * F + cl * 8];
    op[0] = make_float4(v[0], v[1], v[2], v[3]);
    op[1] = make_float4(v[4], v[5], v[6], v[7]);
}

// ---------------- launch ----------------

extern "C" void kernel_launch(void* const* d_in, const int* in_sizes, int n_in,
                              void* d_out, int out_size, void* d_ws, size_t ws_size,
                              hipStream_t stream) {
    const float* x   = (const float*)d_in[0];
    const int*   ei  = (const int*)d_in[1];
    const float* W1  = (const float*)d_in[2];
    const float* as1 = (const float*)d_in[3];
    const float* ad1 = (const float*)d_in[4];
    const float* b1  = (const float*)d_in[5];
    const float* W2  = (const float*)d_in[6];
    const float* as2 = (const float*)d_in[7];
    const float* ad2 = (const float*)d_in[8];
    const float* b2  = (const float*)d_in[9];
    float* out = (float*)d_out;

    char* ws = (char*)d_ws;
    size_t off = 0;
    auto alloc = [&](size_t bytes) {
        void* p = ws + off;
        off += (bytes + 255) & ~(size_t)255;
        return p;
    };
    unsigned short* hb = (unsigned short*)alloc((size_t)NN * F * 2);   // 12.8 MB
    float* als     = (float*)alloc((size_t)NN * HEADS * 4);
    float* ald     = (float*)alloc((size_t)NN * HEADS * 4);
    int*   counts  = (int*)alloc((size_t)NN * 4);
    int*   row_ptr = (int*)alloc((size_t)(NN + 1) * 4);
    int*   bsum    = (int*)alloc((size_t)NB * 4);
    int*   csr_src = (int*)alloc((size_t)ETOT * 4);       // 3.4 MB
    int*   pos     = (int*)alloc((size_t)ETOT * 4);       // 3.4 MB
    unsigned short* wf = (unsigned short*)alloc((size_t)4 * 2048 * 8 * 2);  // 128 KB

    int GG = (NN + RPB - 1) / RPB;         // 391 GEMM blocks (2 per CU, single round)
    int agg_grid = (NN + 15) / 16;         // 3125

    (void)hipMemsetAsync(counts, 0, (size_t)NN * 4, stream);
    wpack_k<<<16, 256, 0, stream>>>(W1, W2, wf);

    // ---- layer 1 GEMM (MFMA, 16 waves/CU) + logits, count tail fused ----
    gemm_mfma<<<GG, 512, 0, stream>>>(x, wf, as1, ad1, hb, als, ald, NN,
                                      ei, counts, pos, GG);
    scan_block_k<<<NB, 1024, 0, stream>>>(counts, row_ptr, bsum, NN);
    scan_add_k<<<(NN + 255) / 256, 256, 0, stream>>>(row_ptr, bsum, NN);
    fill_k<<<(ETOT + 255) / 256, 256, 0, stream>>>(ei, row_ptr, pos, csr_src);
    aggregate<<<agg_grid, 256, 0, stream>>>(hb, als, ald, row_ptr, csr_src, b1, out, 1);

    // ---- layer 2 ----
    gemm_mfma<<<GG, 512, 0, stream>>>(out, wf + (size_t)2 * 2048 * 8, as2, ad2, hb, als, ald, NN,
                                      (const int*)nullptr, (int*)nullptr, (int*)nullptr, GG);
    aggregate<<<agg_grid, 256, 0, stream>>>(hb, als, ald, row_ptr, csr_src, b2, out, 0);
}

// Round 12
// 259.210 us; speedup vs baseline: 1.0654x; 1.0096x over previous
//
#include <hip/hip_runtime.h>
#include <hip/hip_bf16.h>

#define NN 50000
#define EE 800000
#define ETOT (EE + NN)
#define F 128
#define HEADS 4
#define NB ((NN + 1023) / 1024)   // 49 scan chunks

typedef __bf16 bf16x8 __attribute__((ext_vector_type(8)));
typedef float  f32x4  __attribute__((ext_vector_type(4)));

__device__ __forceinline__ unsigned short f32_to_bf16(float f) {
    unsigned int u = __float_as_uint(f);
    u += 0x7fffu + ((u >> 16) & 1u);
    return (unsigned short)(u >> 16);
}
__device__ __forceinline__ float bf16bits_to_f32(unsigned short s) {
    return __uint_as_float(((unsigned int)s) << 16);
}
__device__ __forceinline__ float bflo(unsigned int u) { return __uint_as_float(u << 16); }
__device__ __forceinline__ float bfhi(unsigned int u) { return __uint_as_float(u & 0xffff0000u); }

union BU { unsigned short u[8]; bf16x8 v; };

// ---------------- W pre-pack (B-frag order, hi/lo) + counts zeroing ----------------

__global__ void wpack_k(const float* __restrict__ W1, const float* __restrict__ W2,
                        unsigned short* __restrict__ wf, int* __restrict__ counts) {
    int t = blockIdx.x * blockDim.x + threadIdx.x;   // 0..4095
    for (int i = t; i < NN; i += 4096) counts[i] = 0;
    int which = t >> 11;
    int rem = t & 2047;
    int lane = rem & 63;
    int tile = rem >> 6;          // kt*8+nt
    int kt = tile >> 3, nt = tile & 7;
    int q = lane >> 4, c = lane & 15;
    const float* W = which ? W2 : W1;
    BU vh, vl;
#pragma unroll
    for (int j = 0; j < 8; j++) {
        float w = W[(kt * 32 + q * 8 + j) * F + nt * 16 + c];
        unsigned short hb = f32_to_bf16(w);
        vh.u[j] = hb;
        vl.u[j] = f32_to_bf16(w - bf16bits_to_f32(hb));
    }
    size_t base_h = ((size_t)(which * 2 + 0) * 2048 + tile * 64 + lane) * 8;
    size_t base_l = ((size_t)(which * 2 + 1) * 2048 + tile * 64 + lane) * 8;
    *(bf16x8*)&wf[base_h] = vh.v;
    *(bf16x8*)&wf[base_l] = vl.v;
}

// ---------------- MFMA GEMM: lean registers, 16 rows/wave, kt-prefetch ----------------

__launch_bounds__(256)
__global__ void gemm_mfma(const float* __restrict__ A, const unsigned short* __restrict__ wf,
                          const float* __restrict__ a_src, const float* __restrict__ a_dst,
                          unsigned short* __restrict__ Cb, float* __restrict__ als,
                          float* __restrict__ ald, int M,
                          const int* __restrict__ ei, int* __restrict__ counts,
                          int* __restrict__ pos, int gemm_blocks) {
    __shared__ unsigned char smem[65536];     // W hi+lo; epilogue aliases it
    int tid = threadIdx.x;
    int w = tid >> 6, lane = tid & 63;
    int m = lane & 15, q = lane >> 4;
    int row0 = blockIdx.x * 64 + w * 16;

    // stage 64 KB packed W into LDS
    {
        const uint4* src = (const uint4*)wf;
        uint4* dst = (uint4*)smem;
#pragma unroll
        for (int i = 0; i < 16; i++) dst[tid + i * 256] = src[tid + i * 256];
    }

    int ar = row0 + m; if (ar >= M) ar = 0;          // clamp; stores guarded
    const float* arow = A + (size_t)ar * F + q * 8;
    float4 a0 = *(const float4*)(arow);
    float4 a1 = *(const float4*)(arow + 4);
    __syncthreads();

    const unsigned short* lds_h = (const unsigned short*)smem;
    const unsigned short* lds_l = (const unsigned short*)(smem + 32768);

    f32x4 acc[8];
#pragma unroll
    for (int nt = 0; nt < 8; nt++) acc[nt] = (f32x4){0.f, 0.f, 0.f, 0.f};

#pragma unroll
    for (int kt = 0; kt < 4; kt++) {
        float4 n0, n1;
        if (kt < 3) {                          // prefetch next kt while computing
            n0 = *(const float4*)(arow + (kt + 1) * 32);
            n1 = *(const float4*)(arow + (kt + 1) * 32 + 4);
        }
        float av[8] = {a0.x, a0.y, a0.z, a0.w, a1.x, a1.y, a1.z, a1.w};
        BU ah, al;
#pragma unroll
        for (int j = 0; j < 8; j++) {
            unsigned short hb = f32_to_bf16(av[j]);
            ah.u[j] = hb;
            al.u[j] = f32_to_bf16(av[j] - bf16bits_to_f32(hb));
        }
#pragma unroll
        for (int nt = 0; nt < 8; nt++) {
            int bo = ((kt * 8 + nt) * 64 + lane) * 8;
            bf16x8 bh = *(const bf16x8*)&lds_h[bo];
            bf16x8 bl = *(const bf16x8*)&lds_l[bo];
            acc[nt] = __builtin_amdgcn_mfma_f32_16x16x32_bf16(ah.v, bh, acc[nt], 0, 0, 0);
            acc[nt] = __builtin_amdgcn_mfma_f32_16x16x32_bf16(al.v, bh, acc[nt], 0, 0, 0);
            acc[nt] = __builtin_amdgcn_mfma_f32_16x16x32_bf16(ah.v, bl, acc[nt], 0, 0, 0);
        }
        if (kt < 3) { a0 = n0; a1 = n1; }
    }
    __syncthreads();   // done reading W; reuse LDS for epilogue transpose

    float* L = (float*)smem + w * (16 * 132);
#pragma unroll
    for (int nt = 0; nt < 8; nt++)
#pragma unroll
        for (int r = 0; r < 4; r++)
            L[(q * 4 + r) * 132 + nt * 16 + m] = acc[nt][r];
    // wave-synchronous LDS; in-order DS per wave

    int rr = lane >> 2;
    int head = lane & 3;
    int c0 = head * 32;
    int gr = row0 + rr;
    float v[32];
#pragma unroll
    for (int i = 0; i < 8; i++)
        *(float4*)&v[i * 4] = *(const float4*)&L[rr * 132 + c0 + i * 4];

    if (gr < M) {
#pragma unroll
        for (int i = 0; i < 4; i++) {
            uint4 pk;
            pk.x = (unsigned)f32_to_bf16(v[i * 8 + 0]) | ((unsigned)f32_to_bf16(v[i * 8 + 1]) << 16);
            pk.y = (unsigned)f32_to_bf16(v[i * 8 + 2]) | ((unsigned)f32_to_bf16(v[i * 8 + 3]) << 16);
            pk.z = (unsigned)f32_to_bf16(v[i * 8 + 4]) | ((unsigned)f32_to_bf16(v[i * 8 + 5]) << 16);
            pk.w = (unsigned)f32_to_bf16(v[i * 8 + 6]) | ((unsigned)f32_to_bf16(v[i * 8 + 7]) << 16);
            *(uint4*)&Cb[(size_t)gr * F + c0 + i * 8] = pk;
        }
        float ps = 0.f, pd = 0.f;
#pragma unroll
        for (int i = 0; i < 32; i++) {
            ps += v[i] * a_src[c0 + i];
            pd += v[i] * a_dst[c0 + i];
        }
        als[gr * HEADS + head] = ps;
        ald[gr * HEADS + head] = pd;
    }

    // ---- layer-1 only: degree count + per-edge bucket offset (grid-stride tail) ----
    if (ei) {
        int stride = gemm_blocks * 256;
        for (int e = blockIdx.x * 256 + tid; e < ETOT; e += stride) {
            int dst = (e < EE) ? ei[EE + e] : (e - EE);
            pos[e] = atomicAdd(&counts[dst], 1);
        }
    }
}

// ---------------- per-chunk exclusive scan; chunk totals to bsum ----------------

__launch_bounds__(1024)
__global__ void scan_block_k(const int* __restrict__ counts, int* __restrict__ row_ptr,
                             int* __restrict__ bsum, int n) {
    int tid = threadIdx.x;
    int i = blockIdx.x * 1024 + tid;
    int v = (i < n) ? counts[i] : 0;
    int lane = tid & 63;
    int wave = tid >> 6;
    int x = v;
#pragma unroll
    for (int off = 1; off < 64; off <<= 1) {
        int t = __shfl_up(x, off, 64);
        if (lane >= off) x += t;
    }
    __shared__ int wsum[16];
    if (lane == 63) wsum[wave] = x;
    __syncthreads();
    if (wave == 0) {
        int w = (lane < 16) ? wsum[lane] : 0;
#pragma unroll
        for (int off = 1; off < 16; off <<= 1) {
            int t = __shfl_up(w, off, 64);
            if (lane >= off) w += t;
        }
        if (lane < 16) wsum[lane] = w;
    }
    __syncthreads();
    int base = (wave > 0) ? wsum[wave - 1] : 0;
    int incl = base + x;
    if (i < n) row_ptr[i] = incl - v;          // exclusive WITHIN chunk
    if (tid == 1023) bsum[blockIdx.x] = incl;  // chunk total
}

// helper: wave 0 scans the 49 chunk totals into LDS (exclusive offsets)
__device__ __forceinline__ void chunk_offsets(const int* __restrict__ bsum, int* off_s,
                                              int tid) {
    if (tid < 64) {
        int v = (tid < NB) ? bsum[tid] : 0;
        int x = v;
#pragma unroll
        for (int o = 1; o < 64; o <<= 1) {
            int t = __shfl_up(x, o, 64);
            if (tid >= o) x += t;
        }
        if (tid < NB) off_s[tid] = x - v;
    }
    __syncthreads();
}

// fill: atomic-free scatter; applies chunk offsets on the fly
__launch_bounds__(256)
__global__ void fill_k(const int* __restrict__ ei, const int* __restrict__ row_ptr,
                       const int* __restrict__ bsum, const int* __restrict__ pos,
                       int* __restrict__ csr_src) {
    __shared__ int off_s[NB];
    chunk_offsets(bsum, off_s, threadIdx.x);
    int e = blockIdx.x * blockDim.x + threadIdx.x;
    if (e >= ETOT) return;
    int src, dst;
    if (e < EE) { src = ei[e]; dst = ei[EE + e]; }
    else        { src = e - EE; dst = e - EE; }
    csr_src[row_ptr[dst] + off_s[dst >> 10] + pos[e]] = src;
}

// ---------------- softmax + aggregate: 16-lane group per node, 4-deep pipeline ----------

__launch_bounds__(256)
__global__ void aggregate(const unsigned short* __restrict__ hb, const float* __restrict__ als,
                          const float* __restrict__ ald, const int* __restrict__ row_ptr,
                          const int* __restrict__ bsum, const int* __restrict__ csr_src,
                          const float* __restrict__ bias,
                          float* __restrict__ out, int apply_elu) {
    __shared__ int off_s[NB];
    int tid = threadIdx.x;
    chunk_offsets(bsum, off_s, tid);
    int lane = tid & 63;
    int g  = lane >> 4;                        // node slot within wave
    int cl = lane & 15;                        // channels cl*8 .. cl*8+7
    int n = blockIdx.x * 16 + (tid >> 6) * 4 + g;   // 3125*16 = 50000 exact
    int head = cl >> 2;
    float aldv = ald[n * HEADS + head];
    int jb = row_ptr[n] + off_s[n >> 10];
    int je = (n + 1 < NN) ? (row_ptr[n + 1] + off_s[(n + 1) >> 10]) : ETOT;

    float acc[8];
#pragma unroll
    for (int i = 0; i < 8; i++) acc[i] = 0.f;
    float den = 0.f;

    int j = jb;
    for (; j + 3 < je; j += 4) {               // 4 independent edge-chains
        int s0 = csr_src[j];
        int s1 = csr_src[j + 1];
        int s2 = csr_src[j + 2];
        int s3 = csr_src[j + 3];
        float e0 = als[s0 * HEADS + head];
        float e1 = als[s1 * HEADS + head];
        float e2 = als[s2 * HEADS + head];
        float e3 = als[s3 * HEADS + head];
        uint4 r0 = *(const uint4*)&hb[(size_t)s0 * F + cl * 8];
        uint4 r1 = *(const uint4*)&hb[(size_t)s1 * F + cl * 8];
        uint4 r2 = *(const uint4*)&hb[(size_t)s2 * F + cl * 8];
        uint4 r3 = *(const uint4*)&hb[(size_t)s3 * F + cl * 8];
        e0 += aldv; e1 += aldv; e2 += aldv; e3 += aldv;
        e0 = (e0 > 0.f) ? e0 : 0.2f * e0;
        e1 = (e1 > 0.f) ? e1 : 0.2f * e1;
        e2 = (e2 > 0.f) ? e2 : 0.2f * e2;
        e3 = (e3 > 0.f) ? e3 : 0.2f * e3;
        float p0 = __expf(e0), p1 = __expf(e1), p2 = __expf(e2), p3 = __expf(e3);
        den += (p0 + p1) + (p2 + p3);
        acc[0] += p0 * bflo(r0.x); acc[1] += p0 * bfhi(r0.x);
        acc[2] += p0 * bflo(r0.y); acc[3] += p0 * bfhi(r0.y);
        acc[4] += p0 * bflo(r0.z); acc[5] += p0 * bfhi(r0.z);
        acc[6] += p0 * bflo(r0.w); acc[7] += p0 * bfhi(r0.w);
        acc[0] += p1 * bflo(r1.x); acc[1] += p1 * bfhi(r1.x);
        acc[2] += p1 * bflo(r1.y); acc[3] += p1 * bfhi(r1.y);
        acc[4] += p1 * bflo(r1.z); acc[5] += p1 * bfhi(r1.z);
        acc[6] += p1 * bflo(r1.w); acc[7] += p1 * bfhi(r1.w);
        acc[0] += p2 * bflo(r2.x); acc[1] += p2 * bfhi(r2.x);
        acc[2] += p2 * bflo(r2.y); acc[3] += p2 * bfhi(r2.y);
        acc[4] += p2 * bflo(r2.z); acc[5] += p2 * bfhi(r2.z);
        acc[6] += p2 * bflo(r2.w); acc[7] += p2 * bfhi(r2.w);
        acc[0] += p3 * bflo(r3.x); acc[1] += p3 * bfhi(r3.x);
        acc[2] += p3 * bflo(r3.y); acc[3] += p3 * bfhi(r3.y);
        acc[4] += p3 * bflo(r3.z); acc[5] += p3 * bfhi(r3.z);
        acc[6] += p3 * bflo(r3.w); acc[7] += p3 * bfhi(r3.w);
    }
    for (; j < je; j++) {
        int s = csr_src[j];
        float e = als[s * HEADS + head] + aldv;
        uint4 raw = *(const uint4*)&hb[(size_t)s * F + cl * 8];
        e = (e > 0.f) ? e : 0.2f * e;
        float p = __expf(e);
        den += p;
        acc[0] += p * bflo(raw.x); acc[1] += p * bfhi(raw.x);
        acc[2] += p * bflo(raw.y); acc[3] += p * bfhi(raw.y);
        acc[4] += p * bflo(raw.z); acc[5] += p * bfhi(raw.z);
        acc[6] += p * bflo(raw.w); acc[7] += p * bfhi(raw.w);
    }

    float inv = 1.f / den;
    float v[8];
#pragma unroll
    for (int i = 0; i < 8; i++) {
        v[i] = acc[i] * inv + bias[cl * 8 + i];
        if (apply_elu) v[i] = (v[i] > 0.f) ? v[i] : (__expf(v[i]) - 1.f);
    }
    float4* op = (float4*)&out[(size_t)n * F + cl * 8];
    op[0] = make_float4(v[0], v[1], v[2], v[3]);
    op[1] = make_float4(v[4], v[5], v[6], v[7]);
}

// ---------------- launch ----------------

extern "C" void kernel_launch(void* const* d_in, const int* in_sizes, int n_in,
                              void* d_out, int out_size, void* d_ws, size_t ws_size,
                              hipStream_t stream) {
    const float* x   = (const float*)d_in[0];
    const int*   ei  = (const int*)d_in[1];
    const float* W1  = (const float*)d_in[2];
    const float* as1 = (const float*)d_in[3];
    const float* ad1 = (const float*)d_in[4];
    const float* b1  = (const float*)d_in[5];
    const float* W2  = (const float*)d_in[6];
    const float* as2 = (const float*)d_in[7];
    const float* ad2 = (const float*)d_in[8];
    const float* b2  = (const float*)d_in[9];
    float* out = (float*)d_out;

    char* ws = (char*)d_ws;
    size_t off = 0;
    auto alloc = [&](size_t bytes) {
        void* p = ws + off;
        off += (bytes + 255) & ~(size_t)255;
        return p;
    };
    unsigned short* hb = (unsigned short*)alloc((size_t)NN * F * 2);   // 12.8 MB
    float* als     = (float*)alloc((size_t)NN * HEADS * 4);
    float* ald     = (float*)alloc((size_t)NN * HEADS * 4);
    int*   counts  = (int*)alloc((size_t)NN * 4);
    int*   row_ptr = (int*)alloc((size_t)(NN + 1) * 4);
    int*   bsum    = (int*)alloc((size_t)NB * 4);
    int*   csr_src = (int*)alloc((size_t)ETOT * 4);       // 3.4 MB
    int*   pos     = (int*)alloc((size_t)ETOT * 4);       // 3.4 MB
    unsigned short* wf = (unsigned short*)alloc((size_t)4 * 2048 * 8 * 2);  // 128 KB

    int GG = (NN + 63) / 64;               // 782 GEMM blocks
    int agg_grid = (NN + 15) / 16;         // 3125

    // W pack + counts zeroing (replaces memset)
    wpack_k<<<16, 256, 0, stream>>>(W1, W2, wf, counts);

    // ---- layer 1 GEMM (lean MFMA) + logits, count tail fused ----
    gemm_mfma<<<GG, 256, 0, stream>>>(x, wf, as1, ad1, hb, als, ald, NN,
                                      ei, counts, pos, GG);
    scan_block_k<<<NB, 1024, 0, stream>>>(counts, row_ptr, bsum, NN);
    fill_k<<<(ETOT + 255) / 256, 256, 0, stream>>>(ei, row_ptr, bsum, pos, csr_src);
    aggregate<<<agg_grid, 256, 0, stream>>>(hb, als, ald, row_ptr, bsum, csr_src, b1, out, 1);

    // ---- layer 2 ----
    gemm_mfma<<<GG, 256, 0, stream>>>(out, wf + (size_t)2 * 2048 * 8, as2, ad2, hb, als, ald, NN,
                                      (const int*)nullptr, (int*)nullptr, (int*)nullptr, GG);
    aggregate<<<agg_grid, 256, 0, stream>>>(hb, als, ald, row_ptr, bsum, csr_src, b2, out, 0);
}